// Round 9
// baseline (651.114 us; speedup 1.0000x reference)
//
#include <hip/hip_runtime.h>
#include <cstdint>

#define DIMD  1024
#define NEXP  8
#define HIDN  4096
#define BATCH 4
#define SEQ   2048
#define CAPC  513                  // int(2048*2.0/8)+1
#define RPEX  2304                 // rows per expert, padded to 9*256
#define TPEX  18                   // 128-row tiles per expert
#define TP256 9                    // 256-row tiles per expert
#define MTOT  (NEXP * RPEX)        // 18432
#define MTILES (MTOT / 128)        // 144
#define MT256  (MTOT / 256)        // 72

typedef __bf16 bf16x8 __attribute__((ext_vector_type(8)));
typedef float  f32x4  __attribute__((ext_vector_type(4)));

__device__ __forceinline__ unsigned short f2bf(float f) {
    unsigned u = __float_as_uint(f);
    unsigned r = (u + 0x7FFFu + ((u >> 16) & 1u)) >> 16;
    return (unsigned short)r;
}

// async 16B global->LDS (direct DMA). LDS dest = wave-uniform base + lane*16.
__device__ __forceinline__ void gl16(const unsigned short* g, unsigned short* l) {
    __builtin_amdgcn_global_load_lds(
        (const __attribute__((address_space(1))) void*)g,
        (__attribute__((address_space(3))) void*)l, 16, 0, 0);
}

// Within-XCD supercolumn traversal (128-row tiles). Grid = MTILES * nY.
__device__ __forceinline__ void swz_grp(int GY, int& bx, int& by) {
    int xcd = blockIdx.x & 7, pos = blockIdx.x >> 3;
    int tps = TPEX * GY;
    int sc = pos / tps, rem = pos - sc * tps;
    int bxl = rem / GY, byIn = rem - bxl * GY;
    bx = xcd * TPEX + bxl;
    by = sc * GY + byIn;
}

// ---------------- router: scores_t [B][E][S] = softmax over E ----------------
__global__ __launch_bounds__(64)
void router_kernel(const float* __restrict__ x, const float* __restrict__ rw,
                   float* __restrict__ scores) {
    int token = blockIdx.x;
    int lane  = threadIdx.x;
    const float4* xr = reinterpret_cast<const float4*>(x + (size_t)token * DIMD);
    float4 xv[4];
#pragma unroll
    for (int j = 0; j < 4; ++j) xv[j] = xr[lane * 4 + j];
    float acc[NEXP];
#pragma unroll
    for (int e = 0; e < NEXP; ++e) {
        const float4* wr = reinterpret_cast<const float4*>(rw + (size_t)e * DIMD);
        float a = 0.f;
#pragma unroll
        for (int j = 0; j < 4; ++j) {
            float4 wv = wr[lane * 4 + j];
            a += xv[j].x * wv.x; a += xv[j].y * wv.y;
            a += xv[j].z * wv.z; a += xv[j].w * wv.w;
        }
#pragma unroll
        for (int off = 32; off > 0; off >>= 1) a += __shfl_xor(a, off);
        acc[e] = a;
    }
    float m = acc[0];
#pragma unroll
    for (int e = 1; e < NEXP; ++e) m = fmaxf(m, acc[e]);
    float s = 0.f;
#pragma unroll
    for (int e = 0; e < NEXP; ++e) { acc[e] = expf(acc[e] - m); s += acc[e]; }
    float inv = 1.f / s;
    if (lane == 0) {
        int b = token >> 11;
        int t = token & (SEQ - 1);
#pragma unroll
        for (int e = 0; e < NEXP; ++e)
            scores[((size_t)(b * NEXP + e)) * SEQ + t] = acc[e] * inv;
    }
}

// ------- expert-choice top-k via exact rank (stable, desc), 256 blocks -------
__global__ __launch_bounds__(256)
void topk_kernel(const float* __restrict__ scores, int* __restrict__ sel,
                 float* __restrict__ gate, int* __restrict__ cnt,
                 int* __restrict__ invmap) {
    int be    = blockIdx.x >> 3;
    int chunk = blockIdx.x & 7;
    const float* sc = scores + (size_t)be * SEQ;
    __shared__ float s_sc[SEQ];
    int t = threadIdx.x;
#pragma unroll
    for (int q = 0; q < 8; ++q) s_sc[t + q * 256] = sc[t + q * 256];
    __syncthreads();
    int i = chunk * 256 + t;
    float v = s_sc[i];
    int r = 0;
#pragma unroll 8
    for (int j = 0; j < SEQ; ++j) {
        float u = s_sc[j];
        r += (u > v) || (u == v && j < i);
    }
    if (r < CAPC) {
        sel [(size_t)be * CAPC + r] = i;
        gate[(size_t)be * CAPC + r] = v;
        int b = be >> 3, e = be & 7;
        int tok = b * SEQ + i;
        int p = atomicAdd(cnt + tok, 1);
        invmap[(size_t)tok * 8 + p] = e * RPEX + b * CAPC + r;   // Y row
    }
}

// ---------------- gather: A1 rows (padded) -> bf16 ---------------------------
__global__ __launch_bounds__(256)
void gather_kernel(const float* __restrict__ x, const int* __restrict__ sel,
                   unsigned short* __restrict__ dhi) {
    int gr = blockIdx.x;
    int e  = gr / RPEX;
    int rl = gr - e * RPEX;
    int t  = threadIdx.x;
    size_t dbase = (size_t)gr * DIMD + t * 4;
    if (rl < BATCH * CAPC) {
        int b = rl / CAPC, c = rl - b * CAPC;
        int tok = sel[(size_t)(b * NEXP + e) * CAPC + c];
        float4 v = *reinterpret_cast<const float4*>(x + ((size_t)(b * SEQ + tok)) * DIMD + t * 4);
        ushort4 h;
        h.x = f2bf(v.x); h.y = f2bf(v.y); h.z = f2bf(v.z); h.w = f2bf(v.w);
        *reinterpret_cast<ushort4*>(dhi + dbase) = h;
    } else {
        ushort4 z = {0, 0, 0, 0};
        *reinterpret_cast<ushort4*>(dhi + dbase) = z;
    }
}

// ------ weight transpose of a sub-block: src[k0+kLen][n0+nLen] -> [n][k] bf16 -
__global__ __launch_bounds__(256)
void convT_kernel(const float* __restrict__ src, unsigned short* __restrict__ dhi,
                  int Nsrc, size_t srcEStride, int k0, int n0, int kLen, int nLen) {
    int e = blockIdx.z;
    src += (size_t)e * srcEStride;
    dhi += (size_t)e * kLen * nLen;
    int kb = blockIdx.x * 64, nb = blockIdx.y * 64;
    __shared__ float T[64][65];
    int t = threadIdx.x;
    for (int i = t; i < 1024; i += 256) {
        int r = i >> 4, c4 = (i & 15) * 4;
        float4 v = *reinterpret_cast<const float4*>(
            src + (size_t)(k0 + kb + r) * Nsrc + n0 + nb + c4);
        T[r][c4 + 0] = v.x; T[r][c4 + 1] = v.y; T[r][c4 + 2] = v.z; T[r][c4 + 3] = v.w;
    }
    __syncthreads();
    for (int i = t; i < 1024; i += 256) {
        int n = i >> 4, kc = (i & 15) * 4;
        ushort4 h;
        h.x = f2bf(T[kc + 0][n]); h.y = f2bf(T[kc + 1][n]);
        h.z = f2bf(T[kc + 2][n]); h.w = f2bf(T[kc + 3][n]);
        *reinterpret_cast<ushort4*>(dhi + (size_t)(nb + n) * kLen + kb + kc) = h;
    }
}

// ======== GEMM1: 256x256 tile, 8 waves, BK=32, 3-buffer counted-vmcnt ========
// LDS: 3 x (A[256][32] + B[256][32]) bf16 = 96 KB. Consume tile t from buf t%3,
// stage tile t+2 into buf (t+2)%3 (dead since t-1; iter-top barrier protects).
// vmcnt(4) at tile boundary = tile t+1's 4 loads may stay in flight.
// XOR swizzle (round-8-validated, 0 conflicts): chunk' = chunk ^ ((row>>1)&3).
__global__ __launch_bounds__(512, 2)
void gemm1_8ph(const unsigned short* __restrict__ A,
               const unsigned short* __restrict__ W,
               const float* __restrict__ bias, unsigned short* __restrict__ Hhi,
               size_t wstride, int nbias0, int ldh, int GY) {
    const int K = DIMD;          // 1024
    const int NT = K / 32;       // 32 K-tiles

    int xcd = blockIdx.x & 7, pos = blockIdx.x >> 3;
    int tps = TP256 * GY;
    int sc = pos / tps, rem = pos - sc * tps;
    int bxl = rem / GY, byIn = rem - bxl * GY;
    int bx = xcd * TP256 + bxl;          // 256-row m-tile
    int by = sc * GY + byIn;
    int bn = by * 256;
    int e = bx / TP256;
    const unsigned short* B = W + (size_t)e * wstride;

    int t = threadIdx.x;
    int l = t & 63, wid = t >> 6;
    int wr = wid >> 2, wc = wid & 3;     // 2x4 wave grid: wave owns 128x64
    int grp = l >> 4, li = l & 15;

    __shared__ __align__(16) unsigned short Ab[3][8192];  // [256][32] per buf
    __shared__ __align__(16) unsigned short Bb[3][8192];

    // staging: thread -> (row r, chunk q) within a 128-row half; swizzled src
    int sr = t >> 2, sq = t & 3;
    int qs = (sq ^ ((sr >> 1) & 3)) * 8;
    const unsigned short* gA0 = A + (size_t)(bx * 256 + sr) * K + qs;
    const unsigned short* gA1 = A + (size_t)(bx * 256 + 128 + sr) * K + qs;
    const unsigned short* gB0 = B + (size_t)(bn + sr) * K + qs;
    const unsigned short* gB1 = B + (size_t)(bn + 128 + sr) * K + qs;
    int ldsw = wid * 512;                // per-wave dest base (ushorts)

#define ST_A(bf, tt) do { gl16(gA0 + (tt) * 32, &Ab[bf][ldsw]);        \
                          gl16(gA1 + (tt) * 32, &Ab[bf][4096 + ldsw]); } while (0)
#define ST_B(bf, tt) do { gl16(gB0 + (tt) * 32, &Bb[bf][ldsw]);        \
                          gl16(gB1 + (tt) * 32, &Bb[bf][4096 + ldsw]); } while (0)

    f32x4 acc[8][4];
#pragma unroll
    for (int m = 0; m < 8; ++m)
#pragma unroll
        for (int n = 0; n < 4; ++n) { f32x4 z = {0.f, 0.f, 0.f, 0.f}; acc[m][n] = z; }

    // frag-read bases (validated mapping + swizzle)
    int fsw  = (grp ^ ((li >> 1) & 3)) * 8;
    int aoff = wr * 4096 + li * 32 + fsw;                       // + m*512
    int boff = (wc >> 1) * 4096 + ((wc & 1) * 64 + li) * 32 + fsw;  // + n*512

    // prologue: tiles 0 and 1 (8 loads)
    ST_A(0, 0); ST_B(0, 0);
    ST_A(1, 1); ST_B(1, 1);

    int cb = 0;
    for (int tt = 0; tt < NT; ++tt) {
        if (tt == NT - 1) asm volatile("s_waitcnt vmcnt(0)" ::: "memory");
        else              asm volatile("s_waitcnt vmcnt(4)" ::: "memory");
        __builtin_amdgcn_s_barrier();

        int sb = cb + 2; if (sb >= 3) sb -= 3;
        const unsigned short* ab = &Ab[cb][0];
        const unsigned short* bb = &Bb[cb][0];

        // ---- phase 1: stage A(t+2) | read B + A(m0-3) | 16 MFMA ----
        if (tt + 2 < NT) ST_A(sb, tt + 2);
        bf16x8 bf[4], af[4];
#pragma unroll
        for (int n = 0; n < 4; ++n) bf[n] = *(const bf16x8*)(bb + boff + n * 512);
#pragma unroll
        for (int m = 0; m < 4; ++m) af[m] = *(const bf16x8*)(ab + aoff + m * 512);
        __builtin_amdgcn_s_setprio(1);
#pragma unroll
        for (int m = 0; m < 4; ++m)
#pragma unroll
            for (int n = 0; n < 4; ++n)
                acc[m][n] = __builtin_amdgcn_mfma_f32_16x16x32_bf16(
                    af[m], bf[n], acc[m][n], 0, 0, 0);
        __builtin_amdgcn_s_setprio(0);

        // ---- phase 2: stage B(t+2) | read A(m4-7) | 16 MFMA ----
        if (tt + 2 < NT) ST_B(sb, tt + 2);
#pragma unroll
        for (int m = 0; m < 4; ++m)
            af[m] = *(const bf16x8*)(ab + aoff + (m + 4) * 512);
        __builtin_amdgcn_s_setprio(1);
#pragma unroll
        for (int m = 0; m < 4; ++m)
#pragma unroll
            for (int n = 0; n < 4; ++n)
                acc[m + 4][n] = __builtin_amdgcn_mfma_f32_16x16x32_bf16(
                    af[m], bf[n], acc[m + 4][n], 0, 0, 0);
        __builtin_amdgcn_s_setprio(0);

        ++cb; if (cb == 3) cb = 0;
    }
#undef ST_A
#undef ST_B

    // ---- epilogue: bias + tanh-GELU (|err| ~3e-4 << bf16 rounding) ----
    float bs[4];
#pragma unroll
    for (int n = 0; n < 4; ++n)
        bs[n] = bias[(size_t)e * HIDN + nbias0 + bn + wc * 64 + n * 16 + li];
    const float cc0 = 0.044715f;
    const float cc1 = -2.302118131f;   // -2*0.7978845608*log2(e)
#pragma unroll
    for (int m = 0; m < 8; ++m)
#pragma unroll
        for (int q = 0; q < 4; ++q) {
            int row = bx * 256 + wr * 128 + m * 16 + grp * 4 + q;
#pragma unroll
            for (int n = 0; n < 4; ++n) {
                int col = bn + wc * 64 + n * 16 + li;
                float v = acc[m][n][q] + bs[n];
                float p = __builtin_fmaf(cc0 * v, v * v, v);
                float g = v * __builtin_amdgcn_rcpf(1.0f + exp2f(cc1 * p));
                Hhi[(size_t)row * ldh + col] = f2bf(g);
            }
        }
}

// ===== GEMM2: 128x128 2-phase gload_lds structure (round-8, validated) =======
#define GEMM_PRE(Abase, Bbase, Kc)                                              \
    int t = threadIdx.x;                                                        \
    int l = t & 63, wid = t >> 6;                                               \
    int wr = wid >> 1, wc = wid & 1;                                            \
    int grp = l >> 4, li = l & 15;                                              \
    int fsw  = (grp ^ ((li >> 1) & 3)) * 8;                                     \
    int gsrc = ((l & 3) ^ ((l >> 3) & 3)) * 8;                                  \
    int ra0 = (wid * 2) * 16 + (l >> 2);                                        \
    int ra1 = ra0 + 16;                                                         \
    __shared__ __align__(16) unsigned short As[2][4096];                        \
    __shared__ __align__(16) unsigned short Bs[2][4096];                        \
    int regA = wid * 1024;                                                      \
    const unsigned short* gA0 = (Abase) + (size_t)(bx * 128 + ra0) * (Kc) + gsrc; \
    const unsigned short* gA1 = (Abase) + (size_t)(bx * 128 + ra1) * (Kc) + gsrc; \
    const unsigned short* gB0 = (Bbase) + (size_t)(bn + ra0) * (Kc) + gsrc;     \
    const unsigned short* gB1 = (Bbase) + (size_t)(bn + ra1) * (Kc) + gsrc;     \
    f32x4 acc[4][4];                                                            \
    _Pragma("unroll")                                                           \
    for (int m = 0; m < 4; ++m)                                                 \
        _Pragma("unroll")                                                       \
        for (int n = 0; n < 4; ++n) { f32x4 z = {0.f,0.f,0.f,0.f}; acc[m][n] = z; }

#define STAGE(buf, kt) do {                                                     \
    gl16(gA0 + (kt), &As[buf][regA]);                                           \
    gl16(gA1 + (kt), &As[buf][regA + 512]);                                     \
    gl16(gB0 + (kt), &Bs[buf][regA]);                                           \
    gl16(gB1 + (kt), &Bs[buf][regA + 512]); } while (0)

#define GEMM_LOOP(Kc) do {                                                      \
    STAGE(0, 0);                                                                \
    __syncthreads();                                                            \
    int cur = 0;                                                                \
    for (int kt = 0; kt < (Kc); kt += 32) {                                     \
        if (kt + 32 < (Kc)) STAGE(cur ^ 1, kt + 32);                            \
        bf16x8 ah[4], bh[4];                                                    \
        const unsigned short* aB = &As[cur][wr * 2048 + li * 32 + fsw];         \
        const unsigned short* bB = &Bs[cur][wc * 2048 + li * 32 + fsw];         \
        ah[0] = *(const bf16x8*)(aB);        ah[1] = *(const bf16x8*)(aB + 512); \
        ah[2] = *(const bf16x8*)(aB + 1024); ah[3] = *(const bf16x8*)(aB + 1536); \
        bh[0] = *(const bf16x8*)(bB);        bh[1] = *(const bf16x8*)(bB + 512); \
        bh[2] = *(const bf16x8*)(bB + 1024); bh[3] = *(const bf16x8*)(bB + 1536); \
        _Pragma("unroll")                                                       \
        for (int m = 0; m < 4; ++m)                                             \
            _Pragma("unroll")                                                   \
            for (int n = 0; n < 4; ++n)                                         \
                acc[m][n] = __builtin_amdgcn_mfma_f32_16x16x32_bf16(            \
                    ah[m], bh[n], acc[m][n], 0, 0, 0);                          \
        __syncthreads();                                                        \
        cur ^= 1;                                                               \
    } } while (0)

__global__ __launch_bounds__(256)
void gemm2_mfma(const unsigned short* __restrict__ Ahi,
                const unsigned short* __restrict__ Whi,
                const float* __restrict__ bias, const float* __restrict__ gate,
                float* __restrict__ Y, size_t wstride, int K, int GY) {
    int bx, by; swz_grp(GY, bx, by);
    int bn = by * 128;
    int e = bx / TPEX;
    int rbase_e = (bx - e * TPEX) * 128;
    const unsigned short* Bh = Whi + (size_t)e * wstride;

    GEMM_PRE(Ahi, Bh, K)
    GEMM_LOOP(K);

    int cb = bn + wc * 64;
#pragma unroll
    for (int m = 0; m < 4; ++m)
#pragma unroll
        for (int q = 0; q < 4; ++q) {
            int off = wr * 64 + m * 16 + grp * 4 + q;
            int rloc = rbase_e + off;
            if (rloc < BATCH * CAPC) {
                int b = rloc / CAPC, c = rloc - b * CAPC;
                float g = gate[(size_t)(b * NEXP + e) * CAPC + c];
                size_t grow = (size_t)bx * 128 + off;
#pragma unroll
                for (int n = 0; n < 4; ++n) {
                    int col = cb + n * 16 + li;
                    float v = acc[m][n][q];
                    size_t yo = grow * DIMD + col;
                    if (bias) Y[yo] = g * (v + bias[(size_t)e * DIMD + col]);
                    else      Y[yo] = Y[yo] + g * v;
                }
            }
        }
}

// -------- combine: out[b,s,:] = sum over <=8 gated Y rows (no atomics) -------
__global__ __launch_bounds__(64)
void combine_kernel(const float* __restrict__ Y, const int* __restrict__ cnt,
                    const int* __restrict__ invmap, float* __restrict__ out) {
    int tok = blockIdx.x;
    int lane = threadIdx.x;
    int n = cnt[tok];
    f32x4 acc[4];
#pragma unroll
    for (int q = 0; q < 4; ++q) { f32x4 z = {0.f, 0.f, 0.f, 0.f}; acc[q] = z; }
#pragma unroll
    for (int j = 0; j < 8; ++j) {
        if (j < n) {
            int row = invmap[(size_t)tok * 8 + j];
            const f32x4* yr = reinterpret_cast<const f32x4*>(Y + (size_t)row * DIMD);
#pragma unroll
            for (int q = 0; q < 4; ++q) acc[q] += yr[q * 64 + lane];
        }
    }
    f32x4* op = reinterpret_cast<f32x4*>(out + (size_t)tok * DIMD);
#pragma unroll
    for (int q = 0; q < 4; ++q) op[q * 64 + lane] = acc[q];
}

extern "C" void kernel_launch(void* const* d_in, const int* in_sizes, int n_in,
                              void* d_out, int out_size, void* d_ws, size_t ws_size,
                              hipStream_t stream) {
    (void)in_sizes; (void)n_in; (void)out_size;
    const float* x  = (const float*)d_in[0];
    const float* rw = (const float*)d_in[1];
    const float* w1 = (const float*)d_in[2];
    const float* b1 = (const float*)d_in[3];
    const float* w2 = (const float*)d_in[4];
    const float* b2 = (const float*)d_in[5];
    float* out = (float*)d_out;

    char* ws = (char*)d_ws;
    size_t off = 0;
    auto alloc = [&](size_t bytes) -> char* {
        char* p = ws + off;
        off = (off + bytes + 255) & ~(size_t)255;
        return p;
    };

    float* scores = (float*)alloc((size_t)BATCH * NEXP * SEQ * 4);
    int*   sel    = (int*)  alloc((size_t)BATCH * NEXP * CAPC * 4);
    float* gate   = (float*)alloc((size_t)BATCH * NEXP * CAPC * 4);
    int*   cnt    = (int*)  alloc((size_t)BATCH * SEQ * 4);
    int*   invmap = (int*)  alloc((size_t)BATCH * SEQ * 8 * 4);
    float* Y      = (float*)alloc((size_t)MTOT * DIMD * 4);
    size_t common = off;

    // ---- choose N-chunk factor C ----
    const size_t A1B = (size_t)MTOT * DIMD * 2;          // A1 bf16
    int C = 8;
    for (int c = 1; c <= 8; c <<= 1) {
        size_t wc = (size_t)NEXP * (HIDN / c) * DIMD * 2;
        size_t hc = (size_t)MTOT * (HIDN / c) * 2;
        size_t need = common + A1B + 2 * wc + hc + (8u << 20);
        if (need <= ws_size) { C = c; break; }
    }
    const int HN = HIDN / C;
    const int nY256 = HN / 256;                 // >=2 for C<=8
    const int GY1 = (nY256 < 8) ? nY256 : 8;

    unsigned short* A1h = (unsigned short*)alloc(A1B);
    size_t WCB = (size_t)NEXP * HN * DIMD * 2;
    size_t HCB = (size_t)MTOT * HN * 2;
    unsigned short* W1h = (unsigned short*)alloc(WCB);
    unsigned short* W2h = (unsigned short*)alloc(WCB);
    unsigned short* Hh  = (unsigned short*)alloc(HCB);

    hipMemsetAsync(cnt, 0, (size_t)BATCH * SEQ * 4, stream);
    router_kernel<<<BATCH * SEQ, 64, 0, stream>>>(x, rw, scores);
    topk_kernel<<<BATCH * NEXP * 8, 256, 0, stream>>>(scores, sel, gate, cnt, invmap);
    gather_kernel<<<MTOT, 256, 0, stream>>>(x, sel, A1h);

    for (int c = 0; c < C; ++c) {
        convT_kernel<<<dim3(DIMD / 64, HN / 64, NEXP), 256, 0, stream>>>(
            w1, W1h, HIDN, (size_t)DIMD * HIDN, 0, c * HN, DIMD, HN);
        gemm1_8ph<<<MT256 * nY256, 512, 0, stream>>>(
            A1h, W1h, b1, Hh, (size_t)HN * DIMD, c * HN, HN, GY1);
        convT_kernel<<<dim3(HN / 64, DIMD / 64, NEXP), 256, 0, stream>>>(
            w2, W2h, DIMD, (size_t)HIDN * DIMD, c * HN, 0, HN, DIMD);
        gemm2_mfma<<<MTILES * (DIMD / 128), 256, 0, stream>>>(
            Hh, W2h, (c == 0) ? b2 : nullptr, gate, Y,
            (size_t)DIMD * HN, HN, 4);
    }
    combine_kernel<<<BATCH * SEQ, 64, 0, stream>>>(Y, cnt, invmap, out);
}

// Round 10
// 619.593 us; speedup vs baseline: 1.0509x; 1.0509x over previous
//
#include <hip/hip_runtime.h>
#include <cstdint>

#define DIMD  1024
#define NEXP  8
#define HIDN  4096
#define BATCH 4
#define SEQ   2048
#define CAPC  513                  // int(2048*2.0/8)+1
#define RPEX  2176                 // rows per expert, padded to 17*128
#define TPEX  17                   // 128-row tiles per expert
#define MTOT  (NEXP * RPEX)        // 17408
#define MTILES (MTOT / 128)        // 136

typedef __bf16 bf16x8 __attribute__((ext_vector_type(8)));
typedef float  f32x4  __attribute__((ext_vector_type(4)));

__device__ __forceinline__ unsigned short f2bf(float f) {
    unsigned u = __float_as_uint(f);
    unsigned r = (u + 0x7FFFu + ((u >> 16) & 1u)) >> 16;
    return (unsigned short)r;
}

// async 16B global->LDS (direct DMA). LDS dest = wave-uniform base + lane*16.
__device__ __forceinline__ void gl16(const unsigned short* g, unsigned short* l) {
    __builtin_amdgcn_global_load_lds(
        (const __attribute__((address_space(1))) void*)g,
        (__attribute__((address_space(3))) void*)l, 16, 0, 0);
}

// Within-XCD supercolumn traversal (128-row tiles). Grid = MTILES * nY.
__device__ __forceinline__ void swz_grp(int GY, int& bx, int& by) {
    int xcd = blockIdx.x & 7, pos = blockIdx.x >> 3;
    int tps = TPEX * GY;
    int sc = pos / tps, rem = pos - sc * tps;
    int bxl = rem / GY, byIn = rem - bxl * GY;
    bx = xcd * TPEX + bxl;
    by = sc * GY + byIn;
}

// ---------------- router: scores_t [B][E][S] = softmax over E ----------------
__global__ __launch_bounds__(64)
void router_kernel(const float* __restrict__ x, const float* __restrict__ rw,
                   float* __restrict__ scores) {
    int token = blockIdx.x;
    int lane  = threadIdx.x;
    const float4* xr = reinterpret_cast<const float4*>(x + (size_t)token * DIMD);
    float4 xv[4];
#pragma unroll
    for (int j = 0; j < 4; ++j) xv[j] = xr[lane * 4 + j];
    float acc[NEXP];
#pragma unroll
    for (int e = 0; e < NEXP; ++e) {
        const float4* wr = reinterpret_cast<const float4*>(rw + (size_t)e * DIMD);
        float a = 0.f;
#pragma unroll
        for (int j = 0; j < 4; ++j) {
            float4 wv = wr[lane * 4 + j];
            a += xv[j].x * wv.x; a += xv[j].y * wv.y;
            a += xv[j].z * wv.z; a += xv[j].w * wv.w;
        }
#pragma unroll
        for (int off = 32; off > 0; off >>= 1) a += __shfl_xor(a, off);
        acc[e] = a;
    }
    float m = acc[0];
#pragma unroll
    for (int e = 1; e < NEXP; ++e) m = fmaxf(m, acc[e]);
    float s = 0.f;
#pragma unroll
    for (int e = 0; e < NEXP; ++e) { acc[e] = expf(acc[e] - m); s += acc[e]; }
    float inv = 1.f / s;
    if (lane == 0) {
        int b = token >> 11;
        int t = token & (SEQ - 1);
#pragma unroll
        for (int e = 0; e < NEXP; ++e)
            scores[((size_t)(b * NEXP + e)) * SEQ + t] = acc[e] * inv;
    }
}

// ------- expert-choice top-k via exact rank (stable, desc), 256 blocks -------
__global__ __launch_bounds__(256)
void topk_kernel(const float* __restrict__ scores, int* __restrict__ sel,
                 float* __restrict__ gate, int* __restrict__ cnt,
                 int* __restrict__ invmap) {
    int be    = blockIdx.x >> 3;
    int chunk = blockIdx.x & 7;
    const float* sc = scores + (size_t)be * SEQ;
    __shared__ float s_sc[SEQ];
    int t = threadIdx.x;
#pragma unroll
    for (int q = 0; q < 8; ++q) s_sc[t + q * 256] = sc[t + q * 256];
    __syncthreads();
    int i = chunk * 256 + t;
    float v = s_sc[i];
    int r = 0;
#pragma unroll 8
    for (int j = 0; j < SEQ; ++j) {
        float u = s_sc[j];
        r += (u > v) || (u == v && j < i);
    }
    if (r < CAPC) {
        sel [(size_t)be * CAPC + r] = i;
        gate[(size_t)be * CAPC + r] = v;
        int b = be >> 3, e = be & 7;
        int tok = b * SEQ + i;
        int p = atomicAdd(cnt + tok, 1);
        invmap[(size_t)tok * 8 + p] = e * RPEX + b * CAPC + r;   // Y row
    }
}

// ---------------- gather: A1 rows (padded) -> bf16 ---------------------------
__global__ __launch_bounds__(256)
void gather_kernel(const float* __restrict__ x, const int* __restrict__ sel,
                   unsigned short* __restrict__ dhi) {
    int gr = blockIdx.x;
    int e  = gr / RPEX;
    int rl = gr - e * RPEX;
    int t  = threadIdx.x;
    size_t dbase = (size_t)gr * DIMD + t * 4;
    if (rl < BATCH * CAPC) {
        int b = rl / CAPC, c = rl - b * CAPC;
        int tok = sel[(size_t)(b * NEXP + e) * CAPC + c];
        float4 v = *reinterpret_cast<const float4*>(x + ((size_t)(b * SEQ + tok)) * DIMD + t * 4);
        ushort4 h;
        h.x = f2bf(v.x); h.y = f2bf(v.y); h.z = f2bf(v.z); h.w = f2bf(v.w);
        *reinterpret_cast<ushort4*>(dhi + dbase) = h;
    } else {
        ushort4 z = {0, 0, 0, 0};
        *reinterpret_cast<ushort4*>(dhi + dbase) = z;
    }
}

// ------ weight transpose of a sub-block: src[k0+kLen][n0+nLen] -> [n][k] bf16 -
__global__ __launch_bounds__(256)
void convT_kernel(const float* __restrict__ src, unsigned short* __restrict__ dhi,
                  int Nsrc, size_t srcEStride, int k0, int n0, int kLen, int nLen) {
    int e = blockIdx.z;
    src += (size_t)e * srcEStride;
    dhi += (size_t)e * kLen * nLen;
    int kb = blockIdx.x * 64, nb = blockIdx.y * 64;
    __shared__ float T[64][65];
    int t = threadIdx.x;
    for (int i = t; i < 1024; i += 256) {
        int r = i >> 4, c4 = (i & 15) * 4;
        float4 v = *reinterpret_cast<const float4*>(
            src + (size_t)(k0 + kb + r) * Nsrc + n0 + nb + c4);
        T[r][c4 + 0] = v.x; T[r][c4 + 1] = v.y; T[r][c4 + 2] = v.z; T[r][c4 + 3] = v.w;
    }
    __syncthreads();
    for (int i = t; i < 1024; i += 256) {
        int n = i >> 4, kc = (i & 15) * 4;
        ushort4 h;
        h.x = f2bf(T[kc + 0][n]); h.y = f2bf(T[kc + 1][n]);
        h.z = f2bf(T[kc + 2][n]); h.w = f2bf(T[kc + 3][n]);
        *reinterpret_cast<ushort4*>(dhi + (size_t)(nb + n) * kLen + kb + kc) = h;
    }
}

// ==== single-pass bf16 MFMA GEMMs: gload_lds + XOR swizzle + 3-buf vmcnt =====
// Tile 128x128, BK=32, 256 thr (4 waves, 64x64 each, 4x4 frags 16x16x32).
// LDS [3 buf][128][32] per matrix (48 KB) -> 3 blocks/CU. One barrier per
// K-step; s_waitcnt vmcnt(4) keeps the NEXT tile's 4 loads in flight across
// the barrier (per-wave waitcnt BEFORE s_barrier => after the barrier every
// wave's tile-t loads have landed). Swizzle: chunk' = chunk ^ ((row>>1)&3),
// applied to the GLOBAL source on stage and the read column on frag reads
// (round-8 validated: SQ_LDS_BANK_CONFLICT == 0).

#define GEMM_PRE(Abase, Bbase, Kc)                                              \
    int t = threadIdx.x;                                                        \
    int l = t & 63, wid = t >> 6;                                               \
    int wr = wid >> 1, wc = wid & 1;                                            \
    int grp = l >> 4, li = l & 15;                                              \
    int fsw  = (grp ^ ((li >> 1) & 3)) * 8;                                     \
    int gsrc = ((l & 3) ^ ((l >> 3) & 3)) * 8;                                  \
    int ra0 = (wid * 2) * 16 + (l >> 2);                                        \
    int ra1 = ra0 + 16;                                                         \
    __shared__ __align__(16) unsigned short As[3][4096];                        \
    __shared__ __align__(16) unsigned short Bs[3][4096];                        \
    int regA = wid * 1024;                                                      \
    const unsigned short* gA0 = (Abase) + (size_t)(bx * 128 + ra0) * (Kc) + gsrc; \
    const unsigned short* gA1 = (Abase) + (size_t)(bx * 128 + ra1) * (Kc) + gsrc; \
    const unsigned short* gB0 = (Bbase) + (size_t)(bn + ra0) * (Kc) + gsrc;     \
    const unsigned short* gB1 = (Bbase) + (size_t)(bn + ra1) * (Kc) + gsrc;     \
    f32x4 acc[4][4];                                                            \
    _Pragma("unroll")                                                           \
    for (int m = 0; m < 4; ++m)                                                 \
        _Pragma("unroll")                                                       \
        for (int n = 0; n < 4; ++n) { f32x4 z = {0.f,0.f,0.f,0.f}; acc[m][n] = z; }

#define STAGE(buf, kt) do {                                                     \
    gl16(gA0 + (kt), &As[buf][regA]);                                           \
    gl16(gA1 + (kt), &As[buf][regA + 512]);                                     \
    gl16(gB0 + (kt), &Bs[buf][regA]);                                           \
    gl16(gB1 + (kt), &Bs[buf][regA + 512]); } while (0)

#define GEMM_LOOP(Kc) do {                                                      \
    const int NT = (Kc) / 32;                                                   \
    STAGE(0, 0);                                                                \
    STAGE(1, 32);                                                               \
    int cb = 0;                                                                 \
    for (int tt = 0; tt < NT; ++tt) {                                           \
        if (tt == NT - 1) asm volatile("s_waitcnt vmcnt(0)" ::: "memory");      \
        else              asm volatile("s_waitcnt vmcnt(4)" ::: "memory");      \
        __builtin_amdgcn_s_barrier();                                           \
        int sb = cb + 2; if (sb >= 3) sb -= 3;                                  \
        if (tt + 2 < NT) STAGE(sb, (tt + 2) * 32);                              \
        bf16x8 ah[4], bh[4];                                                    \
        const unsigned short* aB = &As[cb][wr * 2048 + li * 32 + fsw];          \
        const unsigned short* bB = &Bs[cb][wc * 2048 + li * 32 + fsw];          \
        ah[0] = *(const bf16x8*)(aB);        ah[1] = *(const bf16x8*)(aB + 512); \
        ah[2] = *(const bf16x8*)(aB + 1024); ah[3] = *(const bf16x8*)(aB + 1536); \
        bh[0] = *(const bf16x8*)(bB);        bh[1] = *(const bf16x8*)(bB + 512); \
        bh[2] = *(const bf16x8*)(bB + 1024); bh[3] = *(const bf16x8*)(bB + 1536); \
        __builtin_amdgcn_s_setprio(1);                                          \
        _Pragma("unroll")                                                       \
        for (int m = 0; m < 4; ++m)                                             \
            _Pragma("unroll")                                                   \
            for (int n = 0; n < 4; ++n)                                         \
                acc[m][n] = __builtin_amdgcn_mfma_f32_16x16x32_bf16(            \
                    ah[m], bh[n], acc[m][n], 0, 0, 0);                          \
        __builtin_amdgcn_s_setprio(0);                                          \
        ++cb; if (cb == 3) cb = 0;                                              \
    } } while (0)

// -------- GEMM1: H[:,chunk] = gelu(A1 @ W1c^T + b1[nbias0+...]), K=1024 ------
__global__ __launch_bounds__(256)
void gemm1_mfma(const unsigned short* __restrict__ Ahi,
                const unsigned short* __restrict__ Whi,
                const float* __restrict__ bias, unsigned short* __restrict__ Hhi,
                size_t wstride, int nbias0, int ldh, int GY) {
    const int K = DIMD;
    int bx, by; swz_grp(GY, bx, by);
    int bn = by * 128;
    int e = bx / TPEX;
    const unsigned short* Bh = Whi + (size_t)e * wstride;

    GEMM_PRE(Ahi, Bh, K)
    GEMM_LOOP(K);

    int hr0 = bx * 128 + wr * 64;
    int cb2 = bn + wc * 64;
    const float cc0 = 0.044715f;
    const float cc1 = -2.302118131f;   // -2*0.7978845608*log2(e)
#pragma unroll
    for (int m = 0; m < 4; ++m)
#pragma unroll
        for (int q = 0; q < 4; ++q) {
            int row = hr0 + m * 16 + grp * 4 + q;
#pragma unroll
            for (int n = 0; n < 4; ++n) {
                int col = cb2 + n * 16 + li;
                float v = acc[m][n][q] + bias[(size_t)e * HIDN + nbias0 + col];
                float p = __builtin_fmaf(cc0 * v, v * v, v);
                float g = v * __builtin_amdgcn_rcpf(1.0f + exp2f(cc1 * p));
                Hhi[(size_t)row * ldh + col] = f2bf(g);
            }
        }
}

// -------- GEMM2: Y[row] (+)= gate*(Hc @ W2c^T [+ b2]) dense, no atomics ------
__global__ __launch_bounds__(256)
void gemm2_mfma(const unsigned short* __restrict__ Ahi,
                const unsigned short* __restrict__ Whi,
                const float* __restrict__ bias, const float* __restrict__ gate,
                float* __restrict__ Y, size_t wstride, int K, int GY) {
    int bx, by; swz_grp(GY, bx, by);
    int bn = by * 128;
    int e = bx / TPEX;
    int rbase_e = (bx - e * TPEX) * 128;
    const unsigned short* Bh = Whi + (size_t)e * wstride;

    GEMM_PRE(Ahi, Bh, K)
    GEMM_LOOP(K);

    int cb2 = bn + wc * 64;
#pragma unroll
    for (int m = 0; m < 4; ++m)
#pragma unroll
        for (int q = 0; q < 4; ++q) {
            int off = wr * 64 + m * 16 + grp * 4 + q;
            int rloc = rbase_e + off;
            if (rloc < BATCH * CAPC) {
                int b = rloc / CAPC, c = rloc - b * CAPC;
                float g = gate[(size_t)(b * NEXP + e) * CAPC + c];
                size_t grow = (size_t)bx * 128 + off;
#pragma unroll
                for (int n = 0; n < 4; ++n) {
                    int col = cb2 + n * 16 + li;
                    float v = acc[m][n][q];
                    size_t yo = grow * DIMD + col;
                    if (bias) Y[yo] = g * (v + bias[(size_t)e * DIMD + col]);
                    else      Y[yo] = Y[yo] + g * v;
                }
            }
        }
}

// -------- combine: out[b,s,:] = sum over <=8 gated Y rows (no atomics) -------
__global__ __launch_bounds__(64)
void combine_kernel(const float* __restrict__ Y, const int* __restrict__ cnt,
                    const int* __restrict__ invmap, float* __restrict__ out) {
    int tok = blockIdx.x;
    int lane = threadIdx.x;
    int n = cnt[tok];
    f32x4 acc[4];
#pragma unroll
    for (int q = 0; q < 4; ++q) { f32x4 z = {0.f, 0.f, 0.f, 0.f}; acc[q] = z; }
#pragma unroll
    for (int j = 0; j < 8; ++j) {
        if (j < n) {
            int row = invmap[(size_t)tok * 8 + j];
            const f32x4* yr = reinterpret_cast<const f32x4*>(Y + (size_t)row * DIMD);
#pragma unroll
            for (int q = 0; q < 4; ++q) acc[q] += yr[q * 64 + lane];
        }
    }
    f32x4* op = reinterpret_cast<f32x4*>(out + (size_t)tok * DIMD);
#pragma unroll
    for (int q = 0; q < 4; ++q) op[q * 64 + lane] = acc[q];
}

extern "C" void kernel_launch(void* const* d_in, const int* in_sizes, int n_in,
                              void* d_out, int out_size, void* d_ws, size_t ws_size,
                              hipStream_t stream) {
    (void)in_sizes; (void)n_in; (void)out_size;
    const float* x  = (const float*)d_in[0];
    const float* rw = (const float*)d_in[1];
    const float* w1 = (const float*)d_in[2];
    const float* b1 = (const float*)d_in[3];
    const float* w2 = (const float*)d_in[4];
    const float* b2 = (const float*)d_in[5];
    float* out = (float*)d_out;

    char* ws = (char*)d_ws;
    size_t off = 0;
    auto alloc = [&](size_t bytes) -> char* {
        char* p = ws + off;
        off = (off + bytes + 255) & ~(size_t)255;
        return p;
    };

    float* scores = (float*)alloc((size_t)BATCH * NEXP * SEQ * 4);
    int*   sel    = (int*)  alloc((size_t)BATCH * NEXP * CAPC * 4);
    float* gate   = (float*)alloc((size_t)BATCH * NEXP * CAPC * 4);
    int*   cnt    = (int*)  alloc((size_t)BATCH * SEQ * 4);
    int*   invmap = (int*)  alloc((size_t)BATCH * SEQ * 8 * 4);
    float* Y      = (float*)alloc((size_t)MTOT * DIMD * 4);
    size_t common = off;

    // ---- choose N-chunk factor C ----
    const size_t A1B = (size_t)MTOT * DIMD * 2;          // A1 bf16
    int C = 8;
    for (int c = 1; c <= 8; c <<= 1) {
        size_t wc = (size_t)NEXP * (HIDN / c) * DIMD * 2;
        size_t hc = (size_t)MTOT * (HIDN / c) * 2;
        size_t need = common + A1B + 2 * wc + hc + (8u << 20);
        if (need <= ws_size) { C = c; break; }
    }
    const int HN = HIDN / C;
    const int nY1 = HN / 128;
    const int GY1 = (nY1 < 8) ? nY1 : 8;

    unsigned short* A1h = (unsigned short*)alloc(A1B);
    size_t WCB = (size_t)NEXP * HN * DIMD * 2;
    size_t HCB = (size_t)MTOT * HN * 2;
    unsigned short* W1h = (unsigned short*)alloc(WCB);
    unsigned short* W2h = (unsigned short*)alloc(WCB);
    unsigned short* Hh  = (unsigned short*)alloc(HCB);

    hipMemsetAsync(cnt, 0, (size_t)BATCH * SEQ * 4, stream);
    router_kernel<<<BATCH * SEQ, 64, 0, stream>>>(x, rw, scores);
    topk_kernel<<<BATCH * NEXP * 8, 256, 0, stream>>>(scores, sel, gate, cnt, invmap);
    gather_kernel<<<MTOT, 256, 0, stream>>>(x, sel, A1h);

    for (int c = 0; c < C; ++c) {
        convT_kernel<<<dim3(DIMD / 64, HN / 64, NEXP), 256, 0, stream>>>(
            w1, W1h, HIDN, (size_t)DIMD * HIDN, 0, c * HN, DIMD, HN);
        gemm1_mfma<<<MTILES * nY1, 256, 0, stream>>>(
            A1h, W1h, b1, Hh, (size_t)HN * DIMD, c * HN, HN, GY1);
        convT_kernel<<<dim3(HN / 64, DIMD / 64, NEXP), 256, 0, stream>>>(
            w2, W2h, DIMD, (size_t)HIDN * DIMD, c * HN, 0, HN, DIMD);
        gemm2_mfma<<<MTILES * (DIMD / 128), 256, 0, stream>>>(
            Hh, W2h, (c == 0) ? b2 : nullptr, gate, Y,
            (size_t)DIMD * HN, HN, 4);
    }
    combine_kernel<<<BATCH * SEQ, 64, 0, stream>>>(Y, cnt, invmap, out);
}